// Round 5
// baseline (293.494 us; speedup 1.0000x reference)
//
#include <hip/hip_runtime.h>
#include <stdint.h>

typedef __attribute__((ext_vector_type(8))) short bf16x8;
typedef __attribute__((ext_vector_type(4))) float f32x4;

#define GM 8192
#define GN 4096
#define GK 4096
#define KTILES (GK / 64)

__device__ __forceinline__ unsigned short f2bf(float f) {
  union { float f; unsigned int u; } c; c.f = f;
  unsigned int u = c.u;
  unsigned int r = u + 0x7FFFu + ((u >> 16) & 1u);   // round-to-nearest-even
  return (unsigned short)(r >> 16);
}

// ---------------- x (f32) -> bf16, 8 elems/thread ----------------
__global__ __launch_bounds__(256) void cvt_x_kernel(const float* __restrict__ x,
                                                    unsigned short* __restrict__ xb) {
  int i = blockIdx.x * 256 + threadIdx.x;
  const float4* p = (const float4*)x + (size_t)i * 2;
  float4 a = p[0], b = p[1];
  unsigned short t[8] = { f2bf(a.x), f2bf(a.y), f2bf(a.z), f2bf(a.w),
                          f2bf(b.x), f2bf(b.y), f2bf(b.z), f2bf(b.w) };
  int4 pk; __builtin_memcpy(&pk, t, 16);
  ((int4*)xb)[i] = pk;
}

// -------- W_eff = weight + 2 * lora_B @ lora_A -> bf16 --------
// 8x8 register tile per thread: lA float4 loads shared across 8 rows,
// lB reads wave-uniform (scalar path), w/store coalesced float4.
__global__ __launch_bounds__(256) void weff_kernel(const float* __restrict__ w,
                                                   const float* __restrict__ lA,
                                                   const float* __restrict__ lB,
                                                   unsigned short* __restrict__ wb) {
  const int K = GK;
  int idx = blockIdx.x * 256 + threadIdx.x;   // over (N/8)*(K/8) = 512*512
  int cg = idx & 511;                          // col-chunk (consecutive per lane)
  int rg = idx >> 9;                           // row-group (wave-uniform)
  int i0 = cg << 3;
  int o0 = rg << 3;

  float acc[8][8];
#pragma unroll
  for (int r = 0; r < 8; ++r)
#pragma unroll
    for (int c = 0; c < 8; ++c) acc[r][c] = 0.f;

#pragma unroll
  for (int r = 0; r < 16; ++r) {
    float4 a0 = *(const float4*)(lA + (size_t)r * K + i0);
    float4 a1 = *(const float4*)(lA + (size_t)r * K + i0 + 4);
    float av[8] = { a0.x, a0.y, a0.z, a0.w, a1.x, a1.y, a1.z, a1.w };
#pragma unroll
    for (int row = 0; row < 8; ++row) {
      float b = lB[(size_t)(o0 + row) * 16 + r];
#pragma unroll
      for (int c = 0; c < 8; ++c) acc[row][c] += b * av[c];
    }
  }

#pragma unroll
  for (int row = 0; row < 8; ++row) {
    float4 w0 = *(const float4*)(w + (size_t)(o0 + row) * K + i0);
    float4 w1 = *(const float4*)(w + (size_t)(o0 + row) * K + i0 + 4);
    unsigned short t[8] = {
      f2bf(w0.x + 2.0f * acc[row][0]), f2bf(w0.y + 2.0f * acc[row][1]),
      f2bf(w0.z + 2.0f * acc[row][2]), f2bf(w0.w + 2.0f * acc[row][3]),
      f2bf(w1.x + 2.0f * acc[row][4]), f2bf(w1.y + 2.0f * acc[row][5]),
      f2bf(w1.z + 2.0f * acc[row][6]), f2bf(w1.w + 2.0f * acc[row][7]) };
    int4 pk; __builtin_memcpy(&pk, t, 16);
    *(int4*)(wb + (size_t)(o0 + row) * K + i0) = pk;
  }
}

// =================== 256x256 8-phase bf16 GEMM: C = A * B^T ===================
// 8 waves (2M x 4N), 128x64 C per wave, BK=64, 128KB LDS dbuf,
// st_16x32 swizzle (pre-swizzled global src + swizzled ds_read, 0 conflicts).
// Prefetch 3 half-tiles ahead; counted vmcnt(6), never 0 in main loop.

__device__ __forceinline__ void gload16(const unsigned short* g, char* l) {
  __builtin_amdgcn_global_load_lds((__attribute__((address_space(1))) void*)g,
                                   (__attribute__((address_space(3))) void*)l, 16, 0, 0);
}

__device__ __forceinline__ void bar() {
  asm volatile("" ::: "memory");
  __builtin_amdgcn_s_barrier();
  asm volatile("" ::: "memory");
}

#define MFMA_BF16(a, b, c) __builtin_amdgcn_mfma_f32_16x16x32_bf16((a), (b), (c), 0, 0, 0)

// HALF 0: A subtiles {0..3, 8..11}   (avLo, read at P0)
// HALF 1: B subtiles {0,1,4,5,8,9,12,13}   (bv0, read at P0)
// HALF 2: B subtiles {2,3,6,7,10,11,14,15} (bv1, read at P1)
// HALF 3: A subtiles {4..7, 12..15}  (avHi, read at P2)
template <int HALF>
__device__ __forceinline__ void stage_half(const unsigned short* A, const unsigned short* B,
                                           char* smem, int bm0, int bn0, int w, int lane,
                                           int kt, int buf) {
  int sr, isB;
  if constexpr (HALF == 0)      { sr = w + (w & 4);                   isB = 0; }
  else if constexpr (HALF == 1) { sr = ((w >> 1) << 2) + (w & 1);     isB = 1; }
  else if constexpr (HALF == 2) { sr = ((w >> 1) << 2) + (w & 1) + 2; isB = 1; }
  else                          { sr = w + (w & 4) + 4;               isB = 0; }
  const unsigned short* mat = isB ? B : A;
  const int grow = (isB ? bn0 : bm0) + sr * 16 + (lane >> 2);
  const int gcol = ((lane & 3) * 8) ^ ((lane & 32) ? 16 : 0);   // pre-swizzled source col
#pragma unroll
  for (int sc = 0; sc < 2; ++sc) {
    const unsigned short* src = mat + (size_t)grow * GK + kt * 64 + sc * 32 + gcol;
    char* dst = smem + (buf << 16) + (isB ? 32768 : 0) + ((sr * 2 + sc) << 10);
    gload16(src, dst);
  }
}

__device__ __forceinline__ bf16x8 ldsA(const char* smem, int buf, int sr, int sc, int foff) {
  return *(const bf16x8*)(smem + (buf << 16) + ((sr * 2 + sc) << 10) + foff);
}
__device__ __forceinline__ bf16x8 ldsB(const char* smem, int buf, int sr, int sc, int foff) {
  return *(const bf16x8*)(smem + (buf << 16) + 32768 + ((sr * 2 + sc) << 10) + foff);
}

__global__ __launch_bounds__(512, 2) void gemm_bt_kernel(const unsigned short* __restrict__ A,
                                                         const unsigned short* __restrict__ B,
                                                         float* __restrict__ C) {
  __shared__ alignas(16) char smem[131072];

  const int t = threadIdx.x, lane = t & 63, w = t >> 6;
  const int wm = w >> 2, wn = w & 3;     // 2 x 4 wave grid

  // bijective XCD-chunked swizzle: 512 blocks, 512 % 8 == 0
  const int bid = blockIdx.x;
  const int wg  = (bid & 7) * (512 / 8) + (bid >> 3);
  const int bx = wg & 15, by = wg >> 4;
  const int bm0 = by * 256, bn0 = bx * 256;

  // per-lane swizzled fragment byte offset within a 1KB subtile
  int foff = (lane & 15) * 64 + ((lane >> 4) << 4);
  foff ^= ((foff >> 9) & 1) << 5;

  // prologue: tile 0 (all 4 halves) + h0 of tile 1  -> 10 loads in flight
  stage_half<0>(A, B, smem, bm0, bn0, w, lane, 0, 0);
  stage_half<1>(A, B, smem, bm0, bn0, w, lane, 0, 0);
  stage_half<2>(A, B, smem, bm0, bn0, w, lane, 0, 0);
  stage_half<3>(A, B, smem, bm0, bn0, w, lane, 0, 0);
  stage_half<0>(A, B, smem, bm0, bn0, w, lane, 1, 1);
  asm volatile("s_waitcnt vmcnt(6)" ::: "memory");   // h0,h1(0) landed
  bar();

  f32x4 acc[8][4] = {};
  bf16x8 av[4][2], bv0[2][2], bv1[2][2];

  for (int kt = 0; kt < KTILES; ++kt) {
    const int cur = kt & 1;
    const bool n1 = (kt + 1 < KTILES);
    const bool n2 = (kt + 2 < KTILES);

    // ---------------- Phase 0: Q(avLo, bv0); stage h1(kt+1) ----------------
#pragma unroll
    for (int mi = 0; mi < 4; ++mi) {
      av[mi][0] = ldsA(smem, cur, wm * 8 + mi, 0, foff);
      av[mi][1] = ldsA(smem, cur, wm * 8 + mi, 1, foff);
    }
#pragma unroll
    for (int ni = 0; ni < 2; ++ni) {
      bv0[ni][0] = ldsB(smem, cur, wn * 4 + ni, 0, foff);
      bv0[ni][1] = ldsB(smem, cur, wn * 4 + ni, 1, foff);
    }
    if (n1) {
      stage_half<1>(A, B, smem, bm0, bn0, w, lane, kt + 1, cur ^ 1);
      asm volatile("s_waitcnt vmcnt(6)" ::: "memory");   // h2(kt) landed
    } else {
      asm volatile("s_waitcnt vmcnt(2)" ::: "memory");
    }
    bar();
    asm volatile("s_waitcnt lgkmcnt(0)" ::: "memory");
    __builtin_amdgcn_s_setprio(1);
#pragma unroll
    for (int mi = 0; mi < 4; ++mi)
#pragma unroll
      for (int ni = 0; ni < 2; ++ni) {
        acc[mi][ni] = MFMA_BF16(av[mi][0], bv0[ni][0], acc[mi][ni]);
        acc[mi][ni] = MFMA_BF16(av[mi][1], bv0[ni][1], acc[mi][ni]);
      }
    __builtin_amdgcn_s_setprio(0);
    bar();

    // ---------------- Phase 1: Q(avLo, bv1); stage h2(kt+1) ----------------
#pragma unroll
    for (int ni = 0; ni < 2; ++ni) {
      bv1[ni][0] = ldsB(smem, cur, wn * 4 + 2 + ni, 0, foff);
      bv1[ni][1] = ldsB(smem, cur, wn * 4 + 2 + ni, 1, foff);
    }
    if (n1) {
      stage_half<2>(A, B, smem, bm0, bn0, w, lane, kt + 1, cur ^ 1);
      asm volatile("s_waitcnt vmcnt(6)" ::: "memory");   // h3(kt) landed
    } else {
      asm volatile("s_waitcnt vmcnt(0)" ::: "memory");
    }
    bar();
    asm volatile("s_waitcnt lgkmcnt(0)" ::: "memory");
    __builtin_amdgcn_s_setprio(1);
#pragma unroll
    for (int mi = 0; mi < 4; ++mi)
#pragma unroll
      for (int ni = 0; ni < 2; ++ni) {
        acc[mi][2 + ni] = MFMA_BF16(av[mi][0], bv1[ni][0], acc[mi][2 + ni]);
        acc[mi][2 + ni] = MFMA_BF16(av[mi][1], bv1[ni][1], acc[mi][2 + ni]);
      }
    __builtin_amdgcn_s_setprio(0);
    bar();

    // ---------------- Phase 2: Q(avHi, bv1); stage h3(kt+1) ----------------
#pragma unroll
    for (int mi = 0; mi < 4; ++mi) {
      av[mi][0] = ldsA(smem, cur, wm * 8 + 4 + mi, 0, foff);
      av[mi][1] = ldsA(smem, cur, wm * 8 + 4 + mi, 1, foff);
    }
    if (n1) stage_half<3>(A, B, smem, bm0, bn0, w, lane, kt + 1, cur ^ 1);
    bar();
    asm volatile("s_waitcnt lgkmcnt(0)" ::: "memory");
    __builtin_amdgcn_s_setprio(1);
#pragma unroll
    for (int mi = 0; mi < 4; ++mi)
#pragma unroll
      for (int ni = 0; ni < 2; ++ni) {
        acc[4 + mi][2 + ni] = MFMA_BF16(av[mi][0], bv1[ni][0], acc[4 + mi][2 + ni]);
        acc[4 + mi][2 + ni] = MFMA_BF16(av[mi][1], bv1[ni][1], acc[4 + mi][2 + ni]);
      }
    __builtin_amdgcn_s_setprio(0);
    bar();

    // ---------------- Phase 3: Q(avHi, bv0); stage h0(kt+2) ----------------
    if (n2) stage_half<0>(A, B, smem, bm0, bn0, w, lane, kt + 2, cur);
    if (n1) {
      if (n2) asm volatile("s_waitcnt vmcnt(6)" ::: "memory");   // h0,h1(kt+1) landed
      else    asm volatile("s_waitcnt vmcnt(4)" ::: "memory");
    }
    bar();
    __builtin_amdgcn_s_setprio(1);
#pragma unroll
    for (int mi = 0; mi < 4; ++mi)
#pragma unroll
      for (int ni = 0; ni < 2; ++ni) {
        acc[4 + mi][ni] = MFMA_BF16(av[mi][0], bv0[ni][0], acc[4 + mi][ni]);
        acc[4 + mi][ni] = MFMA_BF16(av[mi][1], bv0[ni][1], acc[4 + mi][ni]);
      }
    __builtin_amdgcn_s_setprio(0);
    bar();
  }

  // epilogue: C/D layout col=lane&15, row=4*(lane>>4)+reg
  const int orow = (lane >> 4) << 2;
#pragma unroll
  for (int mi = 0; mi < 8; ++mi) {
#pragma unroll
    for (int ni = 0; ni < 4; ++ni) {
      float* cp = C + (size_t)(bm0 + wm * 128 + mi * 16 + orow) * GN
                    + (bn0 + wn * 64 + ni * 16 + (lane & 15));
#pragma unroll
      for (int r = 0; r < 4; ++r)
        cp[(size_t)r * GN] = acc[mi][ni][r];
    }
  }
}

extern "C" void kernel_launch(void* const* d_in, const int* in_sizes, int n_in,
                              void* d_out, int out_size, void* d_ws, size_t ws_size,
                              hipStream_t stream) {
  const float* x  = (const float*)d_in[0];   // [4,2048,4096] f32
  const float* w  = (const float*)d_in[1];   // [4096,4096]   f32
  const float* lA = (const float*)d_in[2];   // [16,4096]     f32
  const float* lB = (const float*)d_in[3];   // [4096,16]     f32
  float* out = (float*)d_out;                // [4,2048,4096] f32

  const int M = GM, N = GN, K = GK;

  unsigned short* xb = (unsigned short*)d_ws;          // M*K bf16 = 64MB
  unsigned short* wb = xb + (size_t)M * K;             // N*K bf16 = 32MB

  cvt_x_kernel<<<dim3((M * K / 8) / 256), dim3(256), 0, stream>>>(x, xb);
  weff_kernel<<<dim3((N / 8) * (K / 8) / 256), dim3(256), 0, stream>>>(w, lA, lB, wb);
  gemm_bt_kernel<<<dim3((M / 256) * (N / 256)), dim3(512), 0, stream>>>(xb, wb, out);
}

// Round 6
// 292.179 us; speedup vs baseline: 1.0045x; 1.0045x over previous
//
#include <hip/hip_runtime.h>
#include <stdint.h>

typedef __attribute__((ext_vector_type(8))) short bf16x8;
typedef __attribute__((ext_vector_type(4))) float f32x4;

#define GM 8192
#define GN 4096
#define GK 4096
#define KTILES (GK / 64)

__device__ __forceinline__ unsigned short f2bf(float f) {
  union { float f; unsigned int u; } c; c.f = f;
  unsigned int u = c.u;
  unsigned int r = u + 0x7FFFu + ((u >> 16) & 1u);   // round-to-nearest-even
  return (unsigned short)(r >> 16);
}

// ---------------- x (f32) -> bf16, 8 elems/thread ----------------
__global__ __launch_bounds__(256) void cvt_x_kernel(const float* __restrict__ x,
                                                    unsigned short* __restrict__ xb) {
  int i = blockIdx.x * 256 + threadIdx.x;
  const float4* p = (const float4*)x + (size_t)i * 2;
  float4 a = p[0], b = p[1];
  unsigned short t[8] = { f2bf(a.x), f2bf(a.y), f2bf(a.z), f2bf(a.w),
                          f2bf(b.x), f2bf(b.y), f2bf(b.z), f2bf(b.w) };
  int4 pk; __builtin_memcpy(&pk, t, 16);
  ((int4*)xb)[i] = pk;
}

// -------- W_eff = weight + 2 * lora_B @ lora_A -> bf16 --------
// 8x8 register tile per thread: lA float4 loads shared across 8 rows,
// lB reads wave-uniform (scalar path), w/store coalesced float4.
__global__ __launch_bounds__(256) void weff_kernel(const float* __restrict__ w,
                                                   const float* __restrict__ lA,
                                                   const float* __restrict__ lB,
                                                   unsigned short* __restrict__ wb) {
  const int K = GK;
  int idx = blockIdx.x * 256 + threadIdx.x;   // over (N/8)*(K/8) = 512*512
  int cg = idx & 511;                          // col-chunk (consecutive per lane)
  int rg = idx >> 9;                           // row-group (wave-uniform)
  int i0 = cg << 3;
  int o0 = rg << 3;

  float acc[8][8];
#pragma unroll
  for (int r = 0; r < 8; ++r)
#pragma unroll
    for (int c = 0; c < 8; ++c) acc[r][c] = 0.f;

#pragma unroll
  for (int r = 0; r < 16; ++r) {
    float4 a0 = *(const float4*)(lA + (size_t)r * K + i0);
    float4 a1 = *(const float4*)(lA + (size_t)r * K + i0 + 4);
    float av[8] = { a0.x, a0.y, a0.z, a0.w, a1.x, a1.y, a1.z, a1.w };
#pragma unroll
    for (int row = 0; row < 8; ++row) {
      float b = lB[(size_t)(o0 + row) * 16 + r];
#pragma unroll
      for (int c = 0; c < 8; ++c) acc[row][c] += b * av[c];
    }
  }

#pragma unroll
  for (int row = 0; row < 8; ++row) {
    float4 w0 = *(const float4*)(w + (size_t)(o0 + row) * K + i0);
    float4 w1 = *(const float4*)(w + (size_t)(o0 + row) * K + i0 + 4);
    unsigned short t[8] = {
      f2bf(w0.x + 2.0f * acc[row][0]), f2bf(w0.y + 2.0f * acc[row][1]),
      f2bf(w0.z + 2.0f * acc[row][2]), f2bf(w0.w + 2.0f * acc[row][3]),
      f2bf(w1.x + 2.0f * acc[row][4]), f2bf(w1.y + 2.0f * acc[row][5]),
      f2bf(w1.z + 2.0f * acc[row][6]), f2bf(w1.w + 2.0f * acc[row][7]) };
    int4 pk; __builtin_memcpy(&pk, t, 16);
    *(int4*)(wb + (size_t)(o0 + row) * K + i0) = pk;
  }
}

// =================== 256x256 8-phase bf16 GEMM: C = A * B^T ===================
// 8 waves (2M x 4N), 128x64 C per wave, BK=64, 128KB LDS dbuf,
// st_16x32 swizzle (pre-swizzled global src + swizzled ds_read, 0 conflicts).
// Prefetch 3 half-tiles ahead; counted vmcnt(6), never 0 in main loop.

__device__ __forceinline__ void gload16(const unsigned short* g, char* l) {
  __builtin_amdgcn_global_load_lds((__attribute__((address_space(1))) void*)g,
                                   (__attribute__((address_space(3))) void*)l, 16, 0, 0);
}

__device__ __forceinline__ void bar() {
  asm volatile("" ::: "memory");
  __builtin_amdgcn_s_barrier();
  asm volatile("" ::: "memory");
}

#define MFMA_BF16(a, b, c) __builtin_amdgcn_mfma_f32_16x16x32_bf16((a), (b), (c), 0, 0, 0)

// HALF 0: A subtiles {0..3, 8..11}   (avLo, read at P0)
// HALF 1: B subtiles {0,1,4,5,8,9,12,13}   (bv0, read at P0)
// HALF 2: B subtiles {2,3,6,7,10,11,14,15} (bv1, read at P1)
// HALF 3: A subtiles {4..7, 12..15}  (avHi, read at P2)
template <int HALF>
__device__ __forceinline__ void stage_half(const unsigned short* A, const unsigned short* B,
                                           char* smem, int bm0, int bn0, int w, int lane,
                                           int kt, int buf) {
  int sr, isB;
  if constexpr (HALF == 0)      { sr = w + (w & 4);                   isB = 0; }
  else if constexpr (HALF == 1) { sr = ((w >> 1) << 2) + (w & 1);     isB = 1; }
  else if constexpr (HALF == 2) { sr = ((w >> 1) << 2) + (w & 1) + 2; isB = 1; }
  else                          { sr = w + (w & 4) + 4;               isB = 0; }
  const unsigned short* mat = isB ? B : A;
  const int grow = (isB ? bn0 : bm0) + sr * 16 + (lane >> 2);
  const int gcol = ((lane & 3) * 8) ^ ((lane & 32) ? 16 : 0);   // pre-swizzled source col
#pragma unroll
  for (int sc = 0; sc < 2; ++sc) {
    const unsigned short* src = mat + (size_t)grow * GK + kt * 64 + sc * 32 + gcol;
    char* dst = smem + (buf << 16) + (isB ? 32768 : 0) + ((sr * 2 + sc) << 10);
    gload16(src, dst);
  }
}

__device__ __forceinline__ bf16x8 ldsA(const char* smem, int buf, int sr, int sc, int foff) {
  return *(const bf16x8*)(smem + (buf << 16) + ((sr * 2 + sc) << 10) + foff);
}
__device__ __forceinline__ bf16x8 ldsB(const char* smem, int buf, int sr, int sc, int foff) {
  return *(const bf16x8*)(smem + (buf << 16) + 32768 + ((sr * 2 + sc) << 10) + foff);
}

__global__ __launch_bounds__(512, 2) void gemm_bt_kernel(const unsigned short* __restrict__ A,
                                                         const unsigned short* __restrict__ B,
                                                         float* __restrict__ C) {
  __shared__ alignas(16) char smem[131072];

  const int t = threadIdx.x, lane = t & 63, w = t >> 6;
  const int wm = w >> 2, wn = w & 3;     // 2 x 4 wave grid

  // bijective XCD-chunked swizzle: 512 blocks, 512 % 8 == 0
  const int bid = blockIdx.x;
  const int wg  = (bid & 7) * (512 / 8) + (bid >> 3);
  const int bx = wg & 15, by = wg >> 4;
  const int bm0 = by * 256, bn0 = bx * 256;

  // per-lane swizzled fragment byte offset within a 1KB subtile
  int foff = (lane & 15) * 64 + ((lane >> 4) << 4);
  foff ^= ((foff >> 9) & 1) << 5;

  // prologue: tile 0 (all 4 halves) + h0 of tile 1  -> 10 loads in flight
  stage_half<0>(A, B, smem, bm0, bn0, w, lane, 0, 0);
  stage_half<1>(A, B, smem, bm0, bn0, w, lane, 0, 0);
  stage_half<2>(A, B, smem, bm0, bn0, w, lane, 0, 0);
  stage_half<3>(A, B, smem, bm0, bn0, w, lane, 0, 0);
  stage_half<0>(A, B, smem, bm0, bn0, w, lane, 1, 1);
  asm volatile("s_waitcnt vmcnt(6)" ::: "memory");   // h0,h1(0) landed
  bar();

  f32x4 acc[8][4] = {};
  bf16x8 av[4][2], bv0[2][2], bv1[2][2];

  for (int kt = 0; kt < KTILES; ++kt) {
    const int cur = kt & 1;
    const bool n1 = (kt + 1 < KTILES);
    const bool n2 = (kt + 2 < KTILES);

    // ---------------- Phase 0: Q(avLo, bv0); stage h1(kt+1) ----------------
#pragma unroll
    for (int mi = 0; mi < 4; ++mi) {
      av[mi][0] = ldsA(smem, cur, wm * 8 + mi, 0, foff);
      av[mi][1] = ldsA(smem, cur, wm * 8 + mi, 1, foff);
    }
#pragma unroll
    for (int ni = 0; ni < 2; ++ni) {
      bv0[ni][0] = ldsB(smem, cur, wn * 4 + ni, 0, foff);
      bv0[ni][1] = ldsB(smem, cur, wn * 4 + ni, 1, foff);
    }
    if (n1) {
      stage_half<1>(A, B, smem, bm0, bn0, w, lane, kt + 1, cur ^ 1);
      asm volatile("s_waitcnt vmcnt(6)" ::: "memory");   // h2(kt) landed
    } else {
      asm volatile("s_waitcnt vmcnt(2)" ::: "memory");
    }
    bar();
    asm volatile("s_waitcnt lgkmcnt(0)" ::: "memory");
    __builtin_amdgcn_s_setprio(1);
#pragma unroll
    for (int mi = 0; mi < 4; ++mi)
#pragma unroll
      for (int ni = 0; ni < 2; ++ni) {
        acc[mi][ni] = MFMA_BF16(av[mi][0], bv0[ni][0], acc[mi][ni]);
        acc[mi][ni] = MFMA_BF16(av[mi][1], bv0[ni][1], acc[mi][ni]);
      }
    __builtin_amdgcn_s_setprio(0);
    bar();

    // ---------------- Phase 1: Q(avLo, bv1); stage h2(kt+1) ----------------
#pragma unroll
    for (int ni = 0; ni < 2; ++ni) {
      bv1[ni][0] = ldsB(smem, cur, wn * 4 + 2 + ni, 0, foff);
      bv1[ni][1] = ldsB(smem, cur, wn * 4 + 2 + ni, 1, foff);
    }
    if (n1) {
      stage_half<2>(A, B, smem, bm0, bn0, w, lane, kt + 1, cur ^ 1);
      asm volatile("s_waitcnt vmcnt(6)" ::: "memory");   // h3(kt) landed
    } else {
      asm volatile("s_waitcnt vmcnt(0)" ::: "memory");
    }
    bar();
    asm volatile("s_waitcnt lgkmcnt(0)" ::: "memory");
    __builtin_amdgcn_s_setprio(1);
#pragma unroll
    for (int mi = 0; mi < 4; ++mi)
#pragma unroll
      for (int ni = 0; ni < 2; ++ni) {
        acc[mi][2 + ni] = MFMA_BF16(av[mi][0], bv1[ni][0], acc[mi][2 + ni]);
        acc[mi][2 + ni] = MFMA_BF16(av[mi][1], bv1[ni][1], acc[mi][2 + ni]);
      }
    __builtin_amdgcn_s_setprio(0);
    bar();

    // ---------------- Phase 2: Q(avHi, bv1); stage h3(kt+1) ----------------
#pragma unroll
    for (int mi = 0; mi < 4; ++mi) {
      av[mi][0] = ldsA(smem, cur, wm * 8 + 4 + mi, 0, foff);
      av[mi][1] = ldsA(smem, cur, wm * 8 + 4 + mi, 1, foff);
    }
    if (n1) stage_half<3>(A, B, smem, bm0, bn0, w, lane, kt + 1, cur ^ 1);
    bar();
    asm volatile("s_waitcnt lgkmcnt(0)" ::: "memory");
    __builtin_amdgcn_s_setprio(1);
#pragma unroll
    for (int mi = 0; mi < 4; ++mi)
#pragma unroll
      for (int ni = 0; ni < 2; ++ni) {
        acc[4 + mi][2 + ni] = MFMA_BF16(av[mi][0], bv1[ni][0], acc[4 + mi][2 + ni]);
        acc[4 + mi][2 + ni] = MFMA_BF16(av[mi][1], bv1[ni][1], acc[4 + mi][2 + ni]);
      }
    __builtin_amdgcn_s_setprio(0);
    bar();

    // ---------------- Phase 3: Q(avHi, bv0); stage h0(kt+2) ----------------
    if (n2) stage_half<0>(A, B, smem, bm0, bn0, w, lane, kt + 2, cur);
    if (n1) {
      if (n2) asm volatile("s_waitcnt vmcnt(6)" ::: "memory");   // h0,h1(kt+1) landed
      else    asm volatile("s_waitcnt vmcnt(4)" ::: "memory");
    }
    bar();
    __builtin_amdgcn_s_setprio(1);
#pragma unroll
    for (int mi = 0; mi < 4; ++mi)
#pragma unroll
      for (int ni = 0; ni < 2; ++ni) {
        acc[4 + mi][ni] = MFMA_BF16(av[mi][0], bv0[ni][0], acc[4 + mi][ni]);
        acc[4 + mi][ni] = MFMA_BF16(av[mi][1], bv0[ni][1], acc[4 + mi][ni]);
      }
    __builtin_amdgcn_s_setprio(0);
    bar();
  }

  // epilogue: C/D layout col=lane&15, row=4*(lane>>4)+reg
  const int orow = (lane >> 4) << 2;
#pragma unroll
  for (int mi = 0; mi < 8; ++mi) {
#pragma unroll
    for (int ni = 0; ni < 4; ++ni) {
      float* cp = C + (size_t)(bm0 + wm * 128 + mi * 16 + orow) * GN
                    + (bn0 + wn * 64 + ni * 16 + (lane & 15));
#pragma unroll
      for (int r = 0; r < 4; ++r)
        cp[(size_t)r * GN] = acc[mi][ni][r];
    }
  }
}

extern "C" void kernel_launch(void* const* d_in, const int* in_sizes, int n_in,
                              void* d_out, int out_size, void* d_ws, size_t ws_size,
                              hipStream_t stream) {
  const float* x  = (const float*)d_in[0];   // [4,2048,4096] f32
  const float* w  = (const float*)d_in[1];   // [4096,4096]   f32
  const float* lA = (const float*)d_in[2];   // [16,4096]     f32
  const float* lB = (const float*)d_in[3];   // [4096,16]     f32
  float* out = (float*)d_out;                // [4,2048,4096] f32

  const int M = GM, N = GN, K = GK;

  unsigned short* xb = (unsigned short*)d_ws;          // M*K bf16 = 64MB
  unsigned short* wb = xb + (size_t)M * K;             // N*K bf16 = 32MB

  cvt_x_kernel<<<dim3((M * K / 8) / 256), dim3(256), 0, stream>>>(x, xb);
  weff_kernel<<<dim3((N / 8) * (K / 8) / 256), dim3(256), 0, stream>>>(w, lA, lB, wb);
  gemm_bt_kernel<<<dim3((M / 256) * (N / 256)), dim3(512), 0, stream>>>(xb, wb, out);
}

// Round 7
// 288.122 us; speedup vs baseline: 1.0186x; 1.0141x over previous
//
#include <hip/hip_runtime.h>
#include <stdint.h>

typedef __attribute__((ext_vector_type(8))) short bf16x8;
typedef __attribute__((ext_vector_type(4))) float f32x4;

#define GM 8192
#define GN 4096
#define GK 4096
#define KTILES (GK / 64)

__device__ __forceinline__ unsigned short f2bf(float f) {
  union { float f; unsigned int u; } c; c.f = f;
  unsigned int u = c.u;
  unsigned int r = u + 0x7FFFu + ((u >> 16) & 1u);   // round-to-nearest-even
  return (unsigned short)(r >> 16);
}

// ---------------- x (f32) -> bf16, 8 elems/thread ----------------
__global__ __launch_bounds__(256) void cvt_x_kernel(const float* __restrict__ x,
                                                    unsigned short* __restrict__ xb) {
  int i = blockIdx.x * 256 + threadIdx.x;
  const float4* p = (const float4*)x + (size_t)i * 2;
  float4 a = p[0], b = p[1];
  unsigned short t[8] = { f2bf(a.x), f2bf(a.y), f2bf(a.z), f2bf(a.w),
                          f2bf(b.x), f2bf(b.y), f2bf(b.z), f2bf(b.w) };
  int4 pk; __builtin_memcpy(&pk, t, 16);
  ((int4*)xb)[i] = pk;
}

// -------- W_eff = weight + 2 * lora_B @ lora_A -> bf16 --------
__global__ __launch_bounds__(256) void weff_kernel(const float* __restrict__ w,
                                                   const float* __restrict__ lA,
                                                   const float* __restrict__ lB,
                                                   unsigned short* __restrict__ wb) {
  const int K = GK;
  int idx = blockIdx.x * 256 + threadIdx.x;   // over (N/8)*(K/8) = 512*512
  int cg = idx & 511;
  int rg = idx >> 9;
  int i0 = cg << 3;
  int o0 = rg << 3;

  float acc[8][8];
#pragma unroll
  for (int r = 0; r < 8; ++r)
#pragma unroll
    for (int c = 0; c < 8; ++c) acc[r][c] = 0.f;

#pragma unroll
  for (int r = 0; r < 16; ++r) {
    float4 a0 = *(const float4*)(lA + (size_t)r * K + i0);
    float4 a1 = *(const float4*)(lA + (size_t)r * K + i0 + 4);
    float av[8] = { a0.x, a0.y, a0.z, a0.w, a1.x, a1.y, a1.z, a1.w };
#pragma unroll
    for (int row = 0; row < 8; ++row) {
      float b = lB[(size_t)(o0 + row) * 16 + r];
#pragma unroll
      for (int c = 0; c < 8; ++c) acc[row][c] += b * av[c];
    }
  }

#pragma unroll
  for (int row = 0; row < 8; ++row) {
    float4 w0 = *(const float4*)(w + (size_t)(o0 + row) * K + i0);
    float4 w1 = *(const float4*)(w + (size_t)(o0 + row) * K + i0 + 4);
    unsigned short t[8] = {
      f2bf(w0.x + 2.0f * acc[row][0]), f2bf(w0.y + 2.0f * acc[row][1]),
      f2bf(w0.z + 2.0f * acc[row][2]), f2bf(w0.w + 2.0f * acc[row][3]),
      f2bf(w1.x + 2.0f * acc[row][4]), f2bf(w1.y + 2.0f * acc[row][5]),
      f2bf(w1.z + 2.0f * acc[row][6]), f2bf(w1.w + 2.0f * acc[row][7]) };
    int4 pk; __builtin_memcpy(&pk, t, 16);
    *(int4*)(wb + (size_t)(o0 + row) * K + i0) = pk;
  }
}

// =================== 256x256 overlapped 4-phase bf16 GEMM: C = A * B^T ===================
// 8 waves (2M x 4N), 128x64 C per wave, BK=64, 128KB LDS dbuf, st_16x32 swizzle (0 conflicts).
// One barrier per phase; no explicit lgkmcnt (compiler fine-grains); every fragment read is
// issued right after its register's last use, interleaved into the MFMA clusters, so the LDS
// port runs concurrently with the MFMA pipe. vmcnt ledger: P0 6/2, P1 6/0, P3 6/4/-.

__device__ __forceinline__ void gload16(const unsigned short* g, char* l) {
  __builtin_amdgcn_global_load_lds((__attribute__((address_space(1))) void*)g,
                                   (__attribute__((address_space(3))) void*)l, 16, 0, 0);
}

__device__ __forceinline__ void bar() {
  asm volatile("" ::: "memory");
  __builtin_amdgcn_s_barrier();
  asm volatile("" ::: "memory");
}

#define MFMA_BF16(a, b, c) __builtin_amdgcn_mfma_f32_16x16x32_bf16((a), (b), (c), 0, 0, 0)

// HALF 0: A subtiles {0..3, 8..11}   (avLo, consumed P0/P1)
// HALF 1: B subtiles {0,1,4,5,8,9,12,13}   (bv0, consumed P0/P3)
// HALF 2: B subtiles {2,3,6,7,10,11,14,15} (bv1, consumed P1/P2)
// HALF 3: A subtiles {4..7, 12..15}  (avHi, consumed P2/P3)
template <int HALF>
__device__ __forceinline__ void stage_half(const unsigned short* A, const unsigned short* B,
                                           char* smem, int bm0, int bn0, int w, int lane,
                                           int kt, int buf) {
  int sr, isB;
  if constexpr (HALF == 0)      { sr = w + (w & 4);                   isB = 0; }
  else if constexpr (HALF == 1) { sr = ((w >> 1) << 2) + (w & 1);     isB = 1; }
  else if constexpr (HALF == 2) { sr = ((w >> 1) << 2) + (w & 1) + 2; isB = 1; }
  else                          { sr = w + (w & 4) + 4;               isB = 0; }
  const unsigned short* mat = isB ? B : A;
  const int grow = (isB ? bn0 : bm0) + sr * 16 + (lane >> 2);
  const int gcol = ((lane & 3) * 8) ^ ((lane & 32) ? 16 : 0);   // pre-swizzled source col
#pragma unroll
  for (int sc = 0; sc < 2; ++sc) {
    const unsigned short* src = mat + (size_t)grow * GK + kt * 64 + sc * 32 + gcol;
    char* dst = smem + (buf << 16) + (isB ? 32768 : 0) + ((sr * 2 + sc) << 10);
    gload16(src, dst);
  }
}

__device__ __forceinline__ bf16x8 ldsA(const char* smem, int buf, int sr, int sc, int foff) {
  return *(const bf16x8*)(smem + (buf << 16) + ((sr * 2 + sc) << 10) + foff);
}
__device__ __forceinline__ bf16x8 ldsB(const char* smem, int buf, int sr, int sc, int foff) {
  return *(const bf16x8*)(smem + (buf << 16) + 32768 + ((sr * 2 + sc) << 10) + foff);
}

__global__ __launch_bounds__(512, 2) void gemm_bt_kernel(const unsigned short* __restrict__ A,
                                                         const unsigned short* __restrict__ B,
                                                         float* __restrict__ C) {
  __shared__ alignas(16) char smem[131072];

  const int t = threadIdx.x, lane = t & 63, w = t >> 6;
  const int wm = w >> 2, wn = w & 3;     // 2 x 4 wave grid

  // bijective XCD-chunked swizzle: 512 blocks, 512 % 8 == 0
  const int bid = blockIdx.x;
  const int wg  = (bid & 7) * (512 / 8) + (bid >> 3);
  const int bx = wg & 15, by = wg >> 4;
  const int bm0 = by * 256, bn0 = bx * 256;

  // per-lane swizzled fragment byte offset within a 1KB subtile
  int foff = (lane & 15) * 64 + ((lane >> 4) << 4);
  foff ^= ((foff >> 9) & 1) << 5;

  // prologue: tile 0 (all 4 halves) + h0 of tile 1 -> 10 loads in flight
  stage_half<0>(A, B, smem, bm0, bn0, w, lane, 0, 0);
  stage_half<1>(A, B, smem, bm0, bn0, w, lane, 0, 0);
  stage_half<2>(A, B, smem, bm0, bn0, w, lane, 0, 0);
  stage_half<3>(A, B, smem, bm0, bn0, w, lane, 0, 0);
  stage_half<0>(A, B, smem, bm0, bn0, w, lane, 1, 1);
  asm volatile("s_waitcnt vmcnt(6)" ::: "memory");   // h0(0), h1(0) landed
  bar();

  f32x4 acc[8][4] = {};
  bf16x8 av[4][2], bv0[2][2], bv1[2][2];

  // seed avLo(0), bv0(0) (published by prologue barrier)
#pragma unroll
  for (int mi = 0; mi < 4; ++mi) {
    av[mi][0] = ldsA(smem, 0, wm * 8 + mi, 0, foff);
    av[mi][1] = ldsA(smem, 0, wm * 8 + mi, 1, foff);
  }
#pragma unroll
  for (int ni = 0; ni < 2; ++ni) {
    bv0[ni][0] = ldsB(smem, 0, wn * 4 + ni, 0, foff);
    bv0[ni][1] = ldsB(smem, 0, wn * 4 + ni, 1, foff);
  }

  for (int kt = 0; kt < KTILES; ++kt) {
    const int cur = kt & 1, nxt = cur ^ 1;
    const bool n1 = (kt + 1 < KTILES);
    const bool n2 = (kt + 2 < KTILES);

    // ---- P0: (avLo x bv0) -> acc[0..3][0..1]; prefetch bv1(kt) ----
    if (n1) {
      stage_half<1>(A, B, smem, bm0, bn0, w, lane, kt + 1, nxt);
      asm volatile("s_waitcnt vmcnt(6)" ::: "memory");   // h2(kt) landed
    } else {
      asm volatile("s_waitcnt vmcnt(2)" ::: "memory");
    }
    bar();
#pragma unroll
    for (int ni = 0; ni < 2; ++ni) {
      bv1[ni][0] = ldsB(smem, cur, wn * 4 + 2 + ni, 0, foff);
      bv1[ni][1] = ldsB(smem, cur, wn * 4 + 2 + ni, 1, foff);
    }
    __builtin_amdgcn_sched_barrier(0);
    __builtin_amdgcn_s_setprio(1);
#pragma unroll
    for (int mi = 0; mi < 4; ++mi) {
      acc[mi][0] = MFMA_BF16(av[mi][0], bv0[0][0], acc[mi][0]);
      acc[mi][0] = MFMA_BF16(av[mi][1], bv0[0][1], acc[mi][0]);
      acc[mi][1] = MFMA_BF16(av[mi][0], bv0[1][0], acc[mi][1]);
      acc[mi][1] = MFMA_BF16(av[mi][1], bv0[1][1], acc[mi][1]);
    }
    __builtin_amdgcn_s_setprio(0);

    // ---- P1: (avLo x bv1) -> acc[0..3][2..3]; reload av <- avHi(kt) ----
    if (n1) {
      stage_half<2>(A, B, smem, bm0, bn0, w, lane, kt + 1, nxt);
      asm volatile("s_waitcnt vmcnt(6)" ::: "memory");   // h3(kt) landed
    } else {
      asm volatile("s_waitcnt vmcnt(0)" ::: "memory");
    }
    bar();
    __builtin_amdgcn_s_setprio(1);
#pragma unroll
    for (int mi = 0; mi < 4; ++mi) {
      acc[mi][2] = MFMA_BF16(av[mi][0], bv1[0][0], acc[mi][2]);
      acc[mi][2] = MFMA_BF16(av[mi][1], bv1[0][1], acc[mi][2]);
      acc[mi][3] = MFMA_BF16(av[mi][0], bv1[1][0], acc[mi][3]);
      acc[mi][3] = MFMA_BF16(av[mi][1], bv1[1][1], acc[mi][3]);
      av[mi][0] = ldsA(smem, cur, wm * 8 + 4 + mi, 0, foff);   // avHi, published at this B1
      av[mi][1] = ldsA(smem, cur, wm * 8 + 4 + mi, 1, foff);
    }
    __builtin_amdgcn_s_setprio(0);

    // ---- P2: (avHi x bv1) -> acc[4..7][2..3] ----
    if (n1) stage_half<3>(A, B, smem, bm0, bn0, w, lane, kt + 1, nxt);
    bar();
    __builtin_amdgcn_s_setprio(1);
#pragma unroll
    for (int mi = 0; mi < 4; ++mi) {
      acc[4 + mi][2] = MFMA_BF16(av[mi][0], bv1[0][0], acc[4 + mi][2]);
      acc[4 + mi][2] = MFMA_BF16(av[mi][1], bv1[0][1], acc[4 + mi][2]);
      acc[4 + mi][3] = MFMA_BF16(av[mi][0], bv1[1][0], acc[4 + mi][3]);
      acc[4 + mi][3] = MFMA_BF16(av[mi][1], bv1[1][1], acc[4 + mi][3]);
    }
    __builtin_amdgcn_s_setprio(0);

    // ---- P3: (avHi x bv0) -> acc[4..7][0..1]; reload bv0, av <- (kt+1) from buf nxt ----
    if (n2) stage_half<0>(A, B, smem, bm0, bn0, w, lane, kt + 2, cur);
    if (n2)      { asm volatile("s_waitcnt vmcnt(6)" ::: "memory"); }   // h0,h1(kt+1) landed
    else if (n1) { asm volatile("s_waitcnt vmcnt(4)" ::: "memory"); }
    bar();
    __builtin_amdgcn_s_setprio(1);
#pragma unroll
    for (int ni = 0; ni < 2; ++ni) {
#pragma unroll
      for (int mi = 0; mi < 4; ++mi) {
        acc[4 + mi][ni] = MFMA_BF16(av[mi][0], bv0[ni][0], acc[4 + mi][ni]);
        acc[4 + mi][ni] = MFMA_BF16(av[mi][1], bv0[ni][1], acc[4 + mi][ni]);
      }
      if (n1) {
        bv0[ni][0] = ldsB(smem, nxt, wn * 4 + ni, 0, foff);   // bv0(kt+1)
        bv0[ni][1] = ldsB(smem, nxt, wn * 4 + ni, 1, foff);
      }
    }
    if (n1) {
#pragma unroll
      for (int mi = 0; mi < 4; ++mi) {
        av[mi][0] = ldsA(smem, nxt, wm * 8 + mi, 0, foff);    // avLo(kt+1)
        av[mi][1] = ldsA(smem, nxt, wm * 8 + mi, 1, foff);
      }
    }
    __builtin_amdgcn_s_setprio(0);
  }

  // epilogue: C/D layout col=lane&15, row=4*(lane>>4)+reg
  const int orow = (lane >> 4) << 2;
#pragma unroll
  for (int mi = 0; mi < 8; ++mi) {
#pragma unroll
    for (int ni = 0; ni < 4; ++ni) {
      float* cp = C + (size_t)(bm0 + wm * 128 + mi * 16 + orow) * GN
                    + (bn0 + wn * 64 + ni * 16 + (lane & 15));
#pragma unroll
      for (int r = 0; r < 4; ++r)
        cp[(size_t)r * GN] = acc[mi][ni][r];
    }
  }
}

extern "C" void kernel_launch(void* const* d_in, const int* in_sizes, int n_in,
                              void* d_out, int out_size, void* d_ws, size_t ws_size,
                              hipStream_t stream) {
  const float* x  = (const float*)d_in[0];   // [4,2048,4096] f32
  const float* w  = (const float*)d_in[1];   // [4096,4096]   f32
  const float* lA = (const float*)d_in[2];   // [16,4096]     f32
  const float* lB = (const float*)d_in[3];   // [4096,16]     f32
  float* out = (float*)d_out;                // [4,2048,4096] f32

  const int M = GM, N = GN, K = GK;

  unsigned short* xb = (unsigned short*)d_ws;          // M*K bf16 = 64MB
  unsigned short* wb = xb + (size_t)M * K;             // N*K bf16 = 32MB

  cvt_x_kernel<<<dim3((M * K / 8) / 256), dim3(256), 0, stream>>>(x, xb);
  weff_kernel<<<dim3((N / 8) * (K / 8) / 256), dim3(256), 0, stream>>>(w, lA, lB, wb);
  gemm_bt_kernel<<<dim3((M / 256) * (N / 256)), dim3(512), 0, stream>>>(xb, wb, out);
}